// Round 7
// baseline (131.246 us; speedup 1.0000x reference)
//
#include <hip/hip_runtime.h>
#include <math.h>

// ---------------------------------------------------------------------------
// OBB CIoU loss, N independent box pairs -> scalar mean.
// R18: kill the LDS slab -> u64 register sort. R17 solved the occupancy
// mystery: measured occupancy matches a 64 KiB LDS budget (17920B->3blk=41%,
// 35328B->1.85blk=22%), so every round ran at ~3.3 waves/SIMD with per-wave
// VALU duty ~11% -- stall is concurrency-hideable but we never had waves.
// Change: pack key(32b)|bf16x2-payload(32b) into uint64_t; Batcher-63 on u64
// (v_cmp_lt_u64 + 4 cndmask per CE). Payload travels with key ->
// LDS write/read, slot tie-bits, gather indexing all deleted. Net ~+100 VALU
// for LDS/block ~16B -> occupancy becomes VGPR-limited (~2x waves).
// Tie-break: full 32-bit keys; ties need exact equality (coincident verts
// have equal payloads -> order-invariant; distinct collinear-through-centroid
// is measure-zero; strictly safer than the 28-bit keys that passed 6 runs).
// Carried from R14/R17: box1-frame vertex generation with the reference's
// flipped-u quirk (u in (-1,0)), diamond pseudo-angle, native sin/cos,
// atan-identity v-term, frcp divides, exact-reference semantics.
// ---------------------------------------------------------------------------

#define BLOCK 256
#define NV 16

// --- compile-time Batcher odd-even mergesort network for n=16 ---
struct CEList {
    int n;
    unsigned char lo[128];
    unsigned char hi[128];
};

constexpr CEList make_ces16() {
    CEList L{};
    L.n = 0;
    for (int p = 1; p < NV; p <<= 1)
        for (int k = p; k >= 1; k >>= 1)
            for (int j = k % p; j + k < NV; j += 2 * k)
                for (int i = 0; i < k; i++) {
                    int lo = i + j, hi = i + j + k;
                    if (hi < NV && (lo / (2 * p)) == (hi / (2 * p))) {
                        L.lo[L.n] = (unsigned char)lo;
                        L.hi[L.n] = (unsigned char)hi;
                        L.n++;
                    }
                }
    return L;
}

constexpr CEList CES = make_ces16();

__device__ __forceinline__ float frcp(float x) {
    return __builtin_amdgcn_rcpf(x);
}

// Diamond pseudo-angle, no wrap: range [0,4), a cyclic shift of atan2 order.
__device__ __forceinline__ float angle_key(float x, float y) {
    float ax = fabsf(x), ay = fabsf(y);
    float den = ax + ay;
    float r = x * frcp(den);
    r = (den > 0.f) ? r : 0.f;
    return (y >= 0.f) ? (1.f - r) : (3.f + r);
}

// Pack two floats to bf16x2 with round-to-nearest (payload only; keys exact).
__device__ __forceinline__ unsigned int pack_bf2(float x, float y) {
    unsigned int bx = __float_as_uint(x) + 0x8000u;
    unsigned int by = __float_as_uint(y) + 0x8000u;
    return (by & 0xFFFF0000u) | (bx >> 16);
}

// atan(z) for z in [0,1]: degree-11 odd minimax, max err ~1.5e-5 rad.
__device__ __forceinline__ float atan01(float z) {
    float z2 = z * z;
    float p = -0.01172120f;
    p = p * z2 + 0.05265332f;
    p = p * z2 - 0.11643287f;
    p = p * z2 + 0.19354346f;
    p = p * z2 - 0.33262347f;
    p = p * z2 + 0.99997726f;
    return z * p;
}

__device__ __forceinline__ float pair_loss(const float* __restrict__ p,
                                           const float* __restrict__ t,
                                           float wv)
{
    const float MEPS = 1e-6f;           // MODE_EPS
    const float PIf  = 3.14159265358979323846f;
    const float TOLm = 1.f + 2e-6f;     // (1 + 2*tol) slab half-width scale

    float pcx = p[0], pcy = p[1], pw = p[2], ph = p[3], pa = p[4];
    float tcx = t[0], tcy = t[1], tw = t[2], th = t[3], ta = t[4];

    // |angles| bounded -> native sin/cos OK
    float ca = __cosf(pa), sa = __sinf(pa);
    float cb = __cosf(ta), sb = __sinf(ta);

    float hw1 = 0.5f * pw, hh1 = 0.5f * ph;
    float hw2 = 0.5f * tw, hh2 = 0.5f * th;

    // ---- box2 in box1's axis frame ----
    float ddx = tcx - pcx, ddy = tcy - pcy;
    float c2x = ddx * ca + ddy * sa;
    float c2y = ddy * ca - ddx * sa;
    float cd  = cb * ca + sb * sa;      // cos(ta - pa)
    float sd  = sb * ca - cb * sa;      // sin(ta - pa)

    // box2 half-axes: A = hw2*(cd,sd), B = hh2*(-sd,cd)
    // reference corner ring: C0 = q+A-B, C1 = q-A-B, C2 = q-A+B, C3 = q+A+B
    float Axv = hw2 * cd,  Ayv = hw2 * sd;
    float Bxv = -hh2 * sd, Byv = hh2 * cd;
    float qpAx = c2x + Axv, qpAy = c2y + Ayv;
    float qmAx = c2x - Axv, qmAy = c2y - Ayv;
    float C0x = qpAx - Bxv, C0y = qpAy - Byv;
    float C1x = qmAx - Bxv, C1y = qmAy - Byv;
    float C2x = qmAx + Bxv, C2y = qmAy + Byv;
    float C3x = qpAx + Bxv, C3y = qpAy + Byv;

    float Vx[NV], Vy[NV];
    bool  msk[NV];

    // ---- corners1 (= (+-hw1,+-hh1), ring order) inside box2 -> slots 0..3
    // reference p_ab/p_ad window == |du|<hw2*(1+2tol) && |dv|<hh2*(1+2tol)
    {
        float exl = -hw1 - c2x, exh = hw1 - c2x;
        float eyl = -hh1 - c2y, eyh = hh1 - c2y;
        float lw2 = hw2 * TOLm, lh2 = hh2 * TOLm;
        float du, dv;
        du = exh * cd + eyl * sd; dv = eyl * cd - exh * sd;   // K0=( hw1,-hh1)
        msk[0] = (fabsf(du) < lw2) && (fabsf(dv) < lh2);
        Vx[0] = hw1;  Vy[0] = -hh1;
        du = exl * cd + eyl * sd; dv = eyl * cd - exl * sd;   // K1=(-hw1,-hh1)
        msk[1] = (fabsf(du) < lw2) && (fabsf(dv) < lh2);
        Vx[1] = -hw1; Vy[1] = -hh1;
        du = exl * cd + eyh * sd; dv = eyh * cd - exl * sd;   // K2=(-hw1, hh1)
        msk[2] = (fabsf(du) < lw2) && (fabsf(dv) < lh2);
        Vx[2] = -hw1; Vy[2] = hh1;
        du = exh * cd + eyh * sd; dv = eyh * cd - exh * sd;   // K3=( hw1, hh1)
        msk[3] = (fabsf(du) < lw2) && (fabsf(dv) < lh2);
        Vx[3] = hw1;  Vy[3] = hh1;
    }

    // ---- corners2 inside box1 (axis-aligned slab) -> slots 4..7
    {
        float lw1 = hw1 * TOLm, lh1 = hh1 * TOLm;
        msk[4] = (fabsf(C0x) < lw1) && (fabsf(C0y) < lh1);
        Vx[4] = C0x; Vy[4] = C0y;
        msk[5] = (fabsf(C1x) < lw1) && (fabsf(C1y) < lh1);
        Vx[5] = C1x; Vy[5] = C1y;
        msk[6] = (fabsf(C2x) < lw1) && (fabsf(C2y) < lh1);
        Vx[6] = C2x; Vy[6] = C2y;
        msk[7] = (fabsf(C3x) < lw1) && (fabsf(C3y) < lh1);
        Vx[7] = C3x; Vy[7] = C3y;
    }

    // ---- quirky edge crossings -> slots 8..15 (2 per box1 edge) ----
    // box2 edge j: start S_j = C_j, dir D_j: D0=-2A, D1=+2B, D2=+2A, D3=-2B
    {
        float twcd = Axv + Axv, twsd = Ayv + Ayv;          // 2A
        float thsd = -(Bxv + Bxv), thcd = Byv + Byv;       // 2B = (-thsd, thcd)
        float rax = frcp(twcd), ray = frcp(twsd);
        float rbx = frcp(thsd), rby = frcp(thcd);

        float Sx[4]  = { C0x, C1x, C2x, C3x };
        float Sy[4]  = { C0y, C1y, C2y, C3y };
        float Dxe[4] = { -twcd, -thsd, twcd, thsd };
        float Dye[4] = { -twsd, thcd, twsd, -thcd };
        float iDx[4] = { -rax, -rbx, rax, rbx };
        float iDy[4] = { -ray, rby, ray, -rby };

        #pragma unroll
        for (int e1 = 0; e1 < 4; e1++) {
            // box1 ring: e0 bottom(y=-hh1), e1 left(x=-hw1),
            //            e2 top(y=+hh1),   e3 right(x=+hw1)
            const bool horiz = (e1 == 0) || (e1 == 2);
            const float cc   = (e1 == 0) ? -hh1 : (e1 == 1) ? -hw1
                             : (e1 == 2) ?  hh1 :  hw1;
            const float lim  = horiz ? hw1 : hh1;
            float q[4]; bool qm[4];
            #pragma unroll
            for (int j = 0; j < 4; j++) {
                float u = horiz ? (cc - Sy[j]) * iDy[j]
                                : (cc - Sx[j]) * iDx[j];
                float w = horiz ? fmaf(u, Dxe[j], Sx[j])
                                : fmaf(u, Dye[j], Sy[j]);
                // u in (-1,0): frame-exact image of reference's flipped-u
                // mask; |w|<lim == t in (0,1); parallel -> inf/NaN -> reject.
                qm[j] = (u > -1.f) && (u < 0.f) && (fabsf(w) < lim);
                q[j] = w;
            }
            bool mfL = qm[0] || qm[1];
            float fL = qm[0] ? q[0] : q[1];
            bool msL = qm[0] && qm[1];
            bool mfR = qm[2] || qm[3];
            float fR = qm[2] ? q[2] : q[3];
            bool msR = qm[2] && qm[3];
            int s0 = 8 + 2 * e1, s1 = s0 + 1;
            float w0 = mfL ? fL : fR;
            msk[s0]  = mfL || mfR;
            float t2v = msL ? q[1] : fR;
            float w1 = mfL ? t2v : q[3];
            msk[s1]  = msL || (mfL && mfR) || msR;
            if (horiz) { Vx[s0] = w0; Vy[s0] = cc; Vx[s1] = w1; Vy[s1] = cc; }
            else       { Vx[s0] = cc; Vy[s0] = w0; Vx[s1] = cc; Vy[s1] = w1; }
        }
    }

    // ---- centroid of valid verts ----
    float sxs = 0.f, sys = 0.f, cnt = 0.f;
    #pragma unroll
    for (int k = 0; k < NV; k++) {
        sxs += msk[k] ? Vx[k] : 0.f;
        sys += msk[k] ? Vy[k] : 0.f;
        cnt += msk[k] ? 1.f : 0.f;
    }
    float rden = frcp(fmaxf(cnt, 1.f));
    float cenx = sxs * rden, ceny = sys * rden;

    // ---- build u64 records: key(32b, full precision) | bf16x2 payload ----
    unsigned long long k64[NV];
    #pragma unroll
    for (int k = 0; k < NV; k++) {
        float Rx = Vx[k] - cenx, Ry = Vy[k] - ceny;
        float a = msk[k] ? angle_key(Rx, Ry) : 1e7f;  // key from FULL floats
        k64[k] = ((unsigned long long)__float_as_uint(a) << 32)
               | (unsigned long long)pack_bf2(Rx, Ry);
    }

    // ---- sort 16 u64 records (Batcher network, payload travels) ----
    #pragma unroll
    for (int c = 0; c < CES.n; c++) {
        const int lo = CES.lo[c], hi = CES.hi[c];
        unsigned long long a = k64[lo], b = k64[hi];
        bool cl = a < b;
        k64[lo] = cl ? a : b;
        k64[hi] = cl ? b : a;
    }

    // ---- unpack sorted payload; shoelace ----
    const unsigned long long VALID_LIM64 = 0x4974240000000000ull; // 1e6f<<32
    float gx[NV], gy[NV];
    bool  gv[NV];
    #pragma unroll
    for (int k = 0; k < NV; k++) {
        unsigned int pk = (unsigned int)k64[k];
        gx[k] = __uint_as_float(pk << 16);
        gy[k] = __uint_as_float(pk & 0xFFFF0000u);
        gv[k] = k64[k] < VALID_LIM64;
    }
    float fx = gx[0], fy = gy[0];
    float cross = 0.f;
    #pragma unroll
    for (int k = 0; k < NV; k++) {
        int kn = (k + 1) & (NV - 1);     // constant after unroll
        float axv = gv[k]  ? gx[k]  : fx, ayv = gv[k]  ? gy[k]  : fy;
        float bxv = gv[kn] ? gx[kn] : fx, byv = gv[kn] ? gy[kn] : fy;
        cross += axv * byv - ayv * bxv;
    }
    float inter = fabsf(cross) * 0.5f;

    // ---- CIoU ----
    float area1 = pw * ph, area2 = tw * th;
    float iou = inter * frcp(area1 + area2 - inter);
    iou = fminf(fmaxf(iou, 0.f), 1.f);

    float cA = fabsf(ca), sA = fabsf(sa);
    float cB = fabsf(cb), sB = fabsf(sb);
    float dw1 = (pw * cA + ph * sA) * 0.5f, dh1 = (pw * sA + ph * cA) * 0.5f;
    float dw2 = (tw * cB + th * sB) * 0.5f, dh2 = (tw * sB + th * cB) * 0.5f;
    float hp0 = pcx - dw1, hp1 = pcy - dh1, hp2 = pcx + dw1, hp3 = pcy + dh1;
    float ht0 = tcx - dw2, ht1 = tcy - dh2, ht2 = tcx + dw2, ht3 = tcy + dh2;

    float enw = fmaxf(fmaxf(hp2, ht2) - fminf(hp0, ht0), 0.f);
    float enh = fmaxf(fmaxf(hp3, ht3) - fminf(hp1, ht1), 0.f);
    float c2v = enw * enw + enh * enh + MEPS;
    float rho2 = ddx * ddx + ddy * ddy;

    // v-term: atan(r1) - atan(r2) = atan((r1-r2)/(1+r1*r2)), exact for
    // r1*r2 > 0 (both aspect ratios positive). dv is squared -> sign-free.
    float factor = 4.f / (PIf * PIf);
    float r1 = tw * frcp(th + MEPS);
    float r2 = pw * frcp(ph + MEPS);
    float xd = (r1 - r2) * frcp(1.f + r1 * r2);
    float axd = fabsf(xd);
    bool  big = axd > 1.f;
    float z   = big ? frcp(axd) : axd;
    float at  = atan01(z);
    float dv  = big ? ((0.5f * PIf) - at) : at;   // |atan(xd)|
    float v_ = factor * dv * dv;
    float alpha = (iou > 0.5f) ? v_ * frcp(1.f - iou + v_ + MEPS) : 0.f;

    float rhoterm = fminf(fmaxf(rho2 * frcp(c2v), 0.f), 1.f);
    float ciou = iou - (rhoterm + alpha * v_);
    return (1.f - ciou) * wv;
}

__global__ __launch_bounds__(BLOCK)
void obb_ciou_kernel(const float* __restrict__ pred,
                     const float* __restrict__ tgt,
                     const float* __restrict__ wgt,
                     float* __restrict__ out,
                     int N, float invN)
{
    int i = blockIdx.x * BLOCK + (int)threadIdx.x;
    float loss = 0.f;
    if (i < N)
        loss = pair_loss(pred + (size_t)i * 5, tgt + (size_t)i * 5, wgt[i]);

    // ---- reduction: wave shuffle -> LDS -> one atomic per block ----
    #pragma unroll
    for (int off = 32; off > 0; off >>= 1)
        loss += __shfl_down(loss, off, 64);

    __shared__ float red[BLOCK / 64];
    int wave = threadIdx.x >> 6;
    int lane = threadIdx.x & 63;
    if (lane == 0) red[wave] = loss;
    __syncthreads();
    if (threadIdx.x == 0) {
        float s = 0.f;
        #pragma unroll
        for (int w = 0; w < BLOCK / 64; w++) s += red[w];
        atomicAdd(out, s * invN);
    }
}

extern "C" void kernel_launch(void* const* d_in, const int* in_sizes, int n_in,
                              void* d_out, int out_size, void* d_ws, size_t ws_size,
                              hipStream_t stream) {
    const float* pred = (const float*)d_in[0];
    const float* tgt  = (const float*)d_in[1];
    const float* wgt  = (const float*)d_in[2];
    float* out = (float*)d_out;
    int N = in_sizes[2];  // weight element count == N boxes

    hipMemsetAsync(out, 0, sizeof(float) * (size_t)out_size, stream);

    int grid = (N + BLOCK - 1) / BLOCK;
    obb_ciou_kernel<<<grid, BLOCK, 0, stream>>>(pred, tgt, wgt, out, N,
                                                1.f / (float)N);
}

// Round 10
// 128.184 us; speedup vs baseline: 1.0239x; 1.0239x over previous
//
#include <hip/hip_runtime.h>
#include <math.h>

// ---------------------------------------------------------------------------
// OBB CIoU loss, N independent box pairs -> scalar mean.
// R19c: THIRD submit of the f64-comparator-sort experiment (two prior
// attempts died on container infra with no data; R18 ran clean on the same
// harness). Defensive tweak only: __builtin_fmin/__builtin_fmax -> fmin/fmax
// double overloads (same v_min_f64/v_max_f64 codegen, avoids any builtin-
// lowering edge case). Everything else identical to R19.
// Model locked in by R11-R18: time ~ total emitted instructions at a pinned
// ~0.4 instr/cyc/SIMD front-end rate; occupancy (22-44%), LDS, ILP, footprint
// all proven irrelevant (R12/R15/R16/R17/R18 nulls). Only instr count moves
// time. Change vs R18 (59.9us): records key(32b, positive float bits) |
// bf16x2 payload have sign bit 0 -> as positive IEEE f64, VALUE order == BIT
// order. Sort with v_min_f64/v_max_f64: 2 instr/CE vs u64 cmp+4*cndmask = 5
// (63 CEs: -189 instrs). No NaN/inf possible (key <= 1e7f bits). Plus:
// select-once shoelace arrays, validity test on hi word only.
// Carried from R14/R18: box1-frame vertex generation with the reference's
// flipped-u quirk (u in (-1,0)), no-LDS register-record sort, diamond
// pseudo-angle, native sin/cos, atan-identity v-term, frcp divides,
// exact-reference semantics.
// ---------------------------------------------------------------------------

#define BLOCK 256
#define NV 16

// --- compile-time Batcher odd-even mergesort network for n=16 ---
struct CEList {
    int n;
    unsigned char lo[128];
    unsigned char hi[128];
};

constexpr CEList make_ces16() {
    CEList L{};
    L.n = 0;
    for (int p = 1; p < NV; p <<= 1)
        for (int k = p; k >= 1; k >>= 1)
            for (int j = k % p; j + k < NV; j += 2 * k)
                for (int i = 0; i < k; i++) {
                    int lo = i + j, hi = i + j + k;
                    if (hi < NV && (lo / (2 * p)) == (hi / (2 * p))) {
                        L.lo[L.n] = (unsigned char)lo;
                        L.hi[L.n] = (unsigned char)hi;
                        L.n++;
                    }
                }
    return L;
}

constexpr CEList CES = make_ces16();

__device__ __forceinline__ float frcp(float x) {
    return __builtin_amdgcn_rcpf(x);
}

// Diamond pseudo-angle, no wrap: range [0,4), a cyclic shift of atan2 order.
__device__ __forceinline__ float angle_key(float x, float y) {
    float ax = fabsf(x), ay = fabsf(y);
    float den = ax + ay;
    float r = x * frcp(den);
    r = (den > 0.f) ? r : 0.f;
    return (y >= 0.f) ? (1.f - r) : (3.f + r);
}

// Pack two floats to bf16x2 with round-to-nearest (payload only; keys exact).
__device__ __forceinline__ unsigned int pack_bf2(float x, float y) {
    unsigned int bx = __float_as_uint(x) + 0x8000u;
    unsigned int by = __float_as_uint(y) + 0x8000u;
    return (by & 0xFFFF0000u) | (bx >> 16);
}

// atan(z) for z in [0,1]: degree-11 odd minimax, max err ~1.5e-5 rad.
__device__ __forceinline__ float atan01(float z) {
    float z2 = z * z;
    float p = -0.01172120f;
    p = p * z2 + 0.05265332f;
    p = p * z2 - 0.11643287f;
    p = p * z2 + 0.19354346f;
    p = p * z2 - 0.33262347f;
    p = p * z2 + 0.99997726f;
    return z * p;
}

__device__ __forceinline__ float pair_loss(const float* __restrict__ p,
                                           const float* __restrict__ t,
                                           float wv)
{
    const float MEPS = 1e-6f;           // MODE_EPS
    const float PIf  = 3.14159265358979323846f;
    const float TOLm = 1.f + 2e-6f;     // (1 + 2*tol) slab half-width scale

    float pcx = p[0], pcy = p[1], pw = p[2], ph = p[3], pa = p[4];
    float tcx = t[0], tcy = t[1], tw = t[2], th = t[3], ta = t[4];

    // |angles| bounded -> native sin/cos OK
    float ca = __cosf(pa), sa = __sinf(pa);
    float cb = __cosf(ta), sb = __sinf(ta);

    float hw1 = 0.5f * pw, hh1 = 0.5f * ph;
    float hw2 = 0.5f * tw, hh2 = 0.5f * th;

    // ---- box2 in box1's axis frame ----
    float ddx = tcx - pcx, ddy = tcy - pcy;
    float c2x = ddx * ca + ddy * sa;
    float c2y = ddy * ca - ddx * sa;
    float cd  = cb * ca + sb * sa;      // cos(ta - pa)
    float sd  = sb * ca - cb * sa;      // sin(ta - pa)

    // box2 half-axes: A = hw2*(cd,sd), B = hh2*(-sd,cd)
    // reference corner ring: C0 = q+A-B, C1 = q-A-B, C2 = q-A+B, C3 = q+A+B
    float Axv = hw2 * cd,  Ayv = hw2 * sd;
    float Bxv = -hh2 * sd, Byv = hh2 * cd;
    float qpAx = c2x + Axv, qpAy = c2y + Ayv;
    float qmAx = c2x - Axv, qmAy = c2y - Ayv;
    float C0x = qpAx - Bxv, C0y = qpAy - Byv;
    float C1x = qmAx - Bxv, C1y = qmAy - Byv;
    float C2x = qmAx + Bxv, C2y = qmAy + Byv;
    float C3x = qpAx + Bxv, C3y = qpAy + Byv;

    float Vx[NV], Vy[NV];
    bool  msk[NV];

    // ---- corners1 (= (+-hw1,+-hh1), ring order) inside box2 -> slots 0..3
    // reference p_ab/p_ad window == |du|<hw2*(1+2tol) && |dv|<hh2*(1+2tol)
    {
        float exl = -hw1 - c2x, exh = hw1 - c2x;
        float eyl = -hh1 - c2y, eyh = hh1 - c2y;
        float lw2 = hw2 * TOLm, lh2 = hh2 * TOLm;
        float du, dv;
        du = exh * cd + eyl * sd; dv = eyl * cd - exh * sd;   // K0=( hw1,-hh1)
        msk[0] = (fabsf(du) < lw2) && (fabsf(dv) < lh2);
        Vx[0] = hw1;  Vy[0] = -hh1;
        du = exl * cd + eyl * sd; dv = eyl * cd - exl * sd;   // K1=(-hw1,-hh1)
        msk[1] = (fabsf(du) < lw2) && (fabsf(dv) < lh2);
        Vx[1] = -hw1; Vy[1] = -hh1;
        du = exl * cd + eyh * sd; dv = eyh * cd - exl * sd;   // K2=(-hw1, hh1)
        msk[2] = (fabsf(du) < lw2) && (fabsf(dv) < lh2);
        Vx[2] = -hw1; Vy[2] = hh1;
        du = exh * cd + eyh * sd; dv = eyh * cd - exh * sd;   // K3=( hw1, hh1)
        msk[3] = (fabsf(du) < lw2) && (fabsf(dv) < lh2);
        Vx[3] = hw1;  Vy[3] = hh1;
    }

    // ---- corners2 inside box1 (axis-aligned slab) -> slots 4..7
    {
        float lw1 = hw1 * TOLm, lh1 = hh1 * TOLm;
        msk[4] = (fabsf(C0x) < lw1) && (fabsf(C0y) < lh1);
        Vx[4] = C0x; Vy[4] = C0y;
        msk[5] = (fabsf(C1x) < lw1) && (fabsf(C1y) < lh1);
        Vx[5] = C1x; Vy[5] = C1y;
        msk[6] = (fabsf(C2x) < lw1) && (fabsf(C2y) < lh1);
        Vx[6] = C2x; Vy[6] = C2y;
        msk[7] = (fabsf(C3x) < lw1) && (fabsf(C3y) < lh1);
        Vx[7] = C3x; Vy[7] = C3y;
    }

    // ---- quirky edge crossings -> slots 8..15 (2 per box1 edge) ----
    // box2 edge j: start S_j = C_j, dir D_j: D0=-2A, D1=+2B, D2=+2A, D3=-2B
    {
        float twcd = Axv + Axv, twsd = Ayv + Ayv;          // 2A
        float thsd = -(Bxv + Bxv), thcd = Byv + Byv;       // 2B = (-thsd, thcd)
        float rax = frcp(twcd), ray = frcp(twsd);
        float rbx = frcp(thsd), rby = frcp(thcd);

        float Sx[4]  = { C0x, C1x, C2x, C3x };
        float Sy[4]  = { C0y, C1y, C2y, C3y };
        float Dxe[4] = { -twcd, -thsd, twcd, thsd };
        float Dye[4] = { -twsd, thcd, twsd, -thcd };
        float iDx[4] = { -rax, -rbx, rax, rbx };
        float iDy[4] = { -ray, rby, ray, -rby };

        #pragma unroll
        for (int e1 = 0; e1 < 4; e1++) {
            // box1 ring: e0 bottom(y=-hh1), e1 left(x=-hw1),
            //            e2 top(y=+hh1),   e3 right(x=+hw1)
            const bool horiz = (e1 == 0) || (e1 == 2);
            const float cc   = (e1 == 0) ? -hh1 : (e1 == 1) ? -hw1
                             : (e1 == 2) ?  hh1 :  hw1;
            const float lim  = horiz ? hw1 : hh1;
            float q[4]; bool qm[4];
            #pragma unroll
            for (int j = 0; j < 4; j++) {
                float u = horiz ? (cc - Sy[j]) * iDy[j]
                                : (cc - Sx[j]) * iDx[j];
                float w = horiz ? fmaf(u, Dxe[j], Sx[j])
                                : fmaf(u, Dye[j], Sy[j]);
                // u in (-1,0): frame-exact image of reference's flipped-u
                // mask; |w|<lim == t in (0,1); parallel -> inf/NaN -> reject.
                qm[j] = (u > -1.f) && (u < 0.f) && (fabsf(w) < lim);
                q[j] = w;
            }
            bool mfL = qm[0] || qm[1];
            float fL = qm[0] ? q[0] : q[1];
            bool msL = qm[0] && qm[1];
            bool mfR = qm[2] || qm[3];
            float fR = qm[2] ? q[2] : q[3];
            bool msR = qm[2] && qm[3];
            int s0 = 8 + 2 * e1, s1 = s0 + 1;
            float w0 = mfL ? fL : fR;
            msk[s0]  = mfL || mfR;
            float t2v = msL ? q[1] : fR;
            float w1 = mfL ? t2v : q[3];
            msk[s1]  = msL || (mfL && mfR) || msR;
            if (horiz) { Vx[s0] = w0; Vy[s0] = cc; Vx[s1] = w1; Vy[s1] = cc; }
            else       { Vx[s0] = cc; Vy[s0] = w0; Vx[s1] = cc; Vy[s1] = w1; }
        }
    }

    // ---- centroid of valid verts ----
    float sxs = 0.f, sys = 0.f, cnt = 0.f;
    #pragma unroll
    for (int k = 0; k < NV; k++) {
        sxs += msk[k] ? Vx[k] : 0.f;
        sys += msk[k] ? Vy[k] : 0.f;
        cnt += msk[k] ? 1.f : 0.f;
    }
    float rden = frcp(fmaxf(cnt, 1.f));
    float cenx = sxs * rden, ceny = sys * rden;

    // ---- build records: key(32b, positive float bits) | bf16x2 payload ----
    // Sign bit of the f64 view is 0 -> positive double; IEEE order == bit
    // order -> v_min_f64/v_max_f64 implement the u64 comparator in 2 instrs.
    double d64[NV];
    #pragma unroll
    for (int k = 0; k < NV; k++) {
        float Rx = Vx[k] - cenx, Ry = Vy[k] - ceny;
        float a = msk[k] ? angle_key(Rx, Ry) : 1e7f;  // key from FULL floats
        unsigned long long rec =
            ((unsigned long long)__float_as_uint(a) << 32)
          | (unsigned long long)pack_bf2(Rx, Ry);
        d64[k] = __longlong_as_double((long long)rec);
    }

    // ---- sort 16 records (Batcher network, f64 min/max = 2 instr/CE) ----
    #pragma unroll
    for (int c = 0; c < CES.n; c++) {
        const int lo = CES.lo[c], hi = CES.hi[c];
        double a = d64[lo], b = d64[hi];
        d64[lo] = fmin(a, b);
        d64[hi] = fmax(a, b);
    }

    // ---- unpack sorted payload; select-once; shoelace ring ----
    const unsigned int VALID_LIM = 0x49742400u;  // bits of 1e6f
    float sx[NV], sy[NV];
    {
        float gx[NV], gy[NV];
        bool  gv[NV];
        #pragma unroll
        for (int k = 0; k < NV; k++) {
            unsigned long long r = (unsigned long long)__double_as_longlong(d64[k]);
            unsigned int pk = (unsigned int)r;
            gx[k] = __uint_as_float(pk << 16);
            gy[k] = __uint_as_float(pk & 0xFFFF0000u);
            gv[k] = (unsigned int)(r >> 32) < VALID_LIM;
        }
        float fx = gx[0], fy = gy[0];
        #pragma unroll
        for (int k = 0; k < NV; k++) {
            sx[k] = gv[k] ? gx[k] : fx;
            sy[k] = gv[k] ? gy[k] : fy;
        }
    }
    float cross = 0.f;
    #pragma unroll
    for (int k = 0; k < NV; k++) {
        int kn = (k + 1) & (NV - 1);     // constant after unroll
        cross += sx[k] * sy[kn] - sy[k] * sx[kn];
    }
    float inter = fabsf(cross) * 0.5f;

    // ---- CIoU ----
    float area1 = pw * ph, area2 = tw * th;
    float iou = inter * frcp(area1 + area2 - inter);
    iou = fminf(fmaxf(iou, 0.f), 1.f);

    float cA = fabsf(ca), sA = fabsf(sa);
    float cB = fabsf(cb), sB = fabsf(sb);
    float dw1 = (pw * cA + ph * sA) * 0.5f, dh1 = (pw * sA + ph * cA) * 0.5f;
    float dw2 = (tw * cB + th * sB) * 0.5f, dh2 = (tw * sB + th * cB) * 0.5f;
    float hp0 = pcx - dw1, hp1 = pcy - dh1, hp2 = pcx + dw1, hp3 = pcy + dh1;
    float ht0 = tcx - dw2, ht1 = tcy - dh2, ht2 = tcx + dw2, ht3 = tcy + dh2;

    float enw = fmaxf(fmaxf(hp2, ht2) - fminf(hp0, ht0), 0.f);
    float enh = fmaxf(fmaxf(hp3, ht3) - fminf(hp1, ht1), 0.f);
    float c2v = enw * enw + enh * enh + MEPS;
    float rho2 = ddx * ddx + ddy * ddy;

    // v-term: atan(r1) - atan(r2) = atan((r1-r2)/(1+r1*r2)), exact for
    // r1*r2 > 0 (both aspect ratios positive). dv is squared -> sign-free.
    float factor = 4.f / (PIf * PIf);
    float r1 = tw * frcp(th + MEPS);
    float r2 = pw * frcp(ph + MEPS);
    float xd = (r1 - r2) * frcp(1.f + r1 * r2);
    float axd = fabsf(xd);
    bool  big = axd > 1.f;
    float z   = big ? frcp(axd) : axd;
    float at  = atan01(z);
    float dv  = big ? ((0.5f * PIf) - at) : at;   // |atan(xd)|
    float v_ = factor * dv * dv;
    float alpha = (iou > 0.5f) ? v_ * frcp(1.f - iou + v_ + MEPS) : 0.f;

    float rhoterm = fminf(fmaxf(rho2 * frcp(c2v), 0.f), 1.f);
    float ciou = iou - (rhoterm + alpha * v_);
    return (1.f - ciou) * wv;
}

__global__ __launch_bounds__(BLOCK)
void obb_ciou_kernel(const float* __restrict__ pred,
                     const float* __restrict__ tgt,
                     const float* __restrict__ wgt,
                     float* __restrict__ out,
                     int N, float invN)
{
    int i = blockIdx.x * BLOCK + (int)threadIdx.x;
    float loss = 0.f;
    if (i < N)
        loss = pair_loss(pred + (size_t)i * 5, tgt + (size_t)i * 5, wgt[i]);

    // ---- reduction: wave shuffle -> LDS -> one atomic per block ----
    #pragma unroll
    for (int off = 32; off > 0; off >>= 1)
        loss += __shfl_down(loss, off, 64);

    __shared__ float red[BLOCK / 64];
    int wave = threadIdx.x >> 6;
    int lane = threadIdx.x & 63;
    if (lane == 0) red[wave] = loss;
    __syncthreads();
    if (threadIdx.x == 0) {
        float s = 0.f;
        #pragma unroll
        for (int w = 0; w < BLOCK / 64; w++) s += red[w];
        atomicAdd(out, s * invN);
    }
}

extern "C" void kernel_launch(void* const* d_in, const int* in_sizes, int n_in,
                              void* d_out, int out_size, void* d_ws, size_t ws_size,
                              hipStream_t stream) {
    const float* pred = (const float*)d_in[0];
    const float* tgt  = (const float*)d_in[1];
    const float* wgt  = (const float*)d_in[2];
    float* out = (float*)d_out;
    int N = in_sizes[2];  // weight element count == N boxes

    hipMemsetAsync(out, 0, sizeof(float) * (size_t)out_size, stream);

    int grid = (N + BLOCK - 1) / BLOCK;
    obb_ciou_kernel<<<grid, BLOCK, 0, stream>>>(pred, tgt, wgt, out, N,
                                                1.f / (float)N);
}